// Round 2
// baseline (308.262 us; speedup 1.0000x reference)
//
#include <hip/hip_runtime.h>
#include <hip/hip_cooperative_groups.h>

namespace cg = cooperative_groups;

// AP (average precision @ IoU 0.5/0.75) for B=256, N=4000, G=50.
// Strategy: greedy TP matching -> <=50 TPs per (batch,thr); exact stable
// descending-sort ranks of TPs via 2048-bucket counting sort of the 1.024M
// confidences; AP from TP ranks only.
//
// R1: pos 390us latency loop -> LDS. R2-R4: tp stuck ~145us on 1M global
//     hist atomics -> zero-global-atomic design. R5 crash (LDS>64KB).
// R6: 423us. R7: rank one-wave-per-slot; 260. R8: pos1/pos2 split; 204.
// R9: g-outer neutral. R10: bit-exact divide elimination; 191.
// R11: s1/pos2/u64-key bundle neutral; 192.
// R12/R13: cand->global eviction REGRESSED (222us): at grid==CU-count,
//     LDS < 64KB is FREE; eviction added 12.8MB of 8B stores.
// R14: NBKT 1024->2048; 187. R15: pos1+ap -> LDS counting-sort sortap
//     (ranks are DISTINCT ints); 169.8.
// R16: per-phase work models sum to ~70us vs 169.8 measured, and every
//     kernel is <44us (all top-5 rocprof rows are harness fills) -> the
//     residual lives in 6 serial dispatch boundaries. Fuse EVERYTHING into
//     one cooperative kernel (256 blocks x 1024 thr = 1 block/CU, LDS
//     unioned 63.4KB, 4 grid.sync()s). Phase bodies verbatim; s2 absorbed
//     into scatter phase (redundant per-block 2048-scan, saves a sync).

#define B_ 256
#define N_ 4000
#define G_ 50
#define M_ (B_ * N_)        // 1,024,000 proposals total
#define NL_ (B_ * G_)       // 12,800 labels total (= n_labels)
#define NBKT 2048

// exact decision thresholds: thr + 2^-25
#define M0_ 0x1.000001p-1   // 0.5  + 2^-25
#define M1_ 0x1.800001p-1   // 0.75 + 2^-25

typedef unsigned long long u64;

__device__ __forceinline__ unsigned bucket_of(float c) {
    unsigned b = (unsigned)(c * 2048.0f);
    return b > (NBKT - 1) ? (NBKT - 1) : b;
}

// ---- LDS union across phases (max 63.4 KiB, 1 block/CU so free) ----------
struct TpS {
    float2 gtl[G_];            // 400 B
    u64 cand[2][G_][64];       // 51.2 KiB
    unsigned hls[NBKT];        // 8 KiB
    int lcnt[2];
};                             // 59.8 KiB
struct S1S { unsigned sc[4][256]; };                       // 4 KiB
struct ScS { unsigned baseB[NBKT]; unsigned lofs[NBKT]; }; // 16 KiB
struct ApS {
    int sr[NL_];                                           // 51.2 KiB
    union { unsigned part[1024]; float cmax[1024]; } u1;   // 4 KiB
    union { unsigned hist[NBKT]; double red[1024]; } u2;   // 8 KiB
};                             // 63.4 KiB
union SmemU { TpS tp; S1S s1; ScS sc; ApS ap; };

__global__ __launch_bounds__(1024) void mega_kernel(
    const float* __restrict__ seg,    // [B,N,2]
    const float* __restrict__ gts,    // [B,G,2]
    const float* __restrict__ conf,   // [B,N]
    int* __restrict__ tpIdx,          // [2][NL_]
    int* __restrict__ cnt,            // [2][B_]
    unsigned short* __restrict__ pbh, // [B_][NBKT] hist -> exclusive prefix
    unsigned* __restrict__ total,     // [NBKT]
    unsigned* __restrict__ binStartG, // [NBKT]
    u64* __restrict__ sKey,           // [M_]
    int* __restrict__ tpRank,         // [2][NL_]
    float* __restrict__ out)          // [2]
{
    cg::grid_group grid = cg::this_grid();
    const int tid  = threadIdx.x;
    const int lane = tid & 63;
    const int wv   = tid >> 6;            // wave id 0..15
    const int b    = blockIdx.x;

    __shared__ SmemU smem;

    // ================= Phase 0: tp (block == batch) =======================
    {
        #pragma unroll
        for (int k = 0; k < NBKT / 1024; ++k) smem.tp.hls[k * 1024 + tid] = 0u;
        if (tid < G_) smem.tp.gtl[tid] = ((const float2*)gts)[b * G_ + tid];
        if (tid < 2) smem.tp.lcnt[tid] = 0;
        __syncthreads();

        // LDS-private histogram of this batch's 4000 scores
        const float* cb = conf + (size_t)b * N_;
        #pragma unroll
        for (int s = 0; s < 4; ++s) {
            int n = s * 1024 + tid;
            if (n < N_) atomicAdd(&smem.tp.hls[bucket_of(cb[n])], 1u);
        }

        // Phase A (g outer): props in registers, gt read once per g.
        const float2* sb = (const float2*)(seg + (size_t)b * (N_ * 2));
        float pmin[4], pmax[4], plen[4];
        #pragma unroll
        for (int s = 0; s < 4; ++s) {
            int n = s * 1024 + tid;
            if (n < N_) { float2 v = sb[n]; pmin[s] = v.x; pmax[s] = v.y; }
            else { pmin[s] = 1e9f; pmax[s] = 1e9f; }   // sentinel -> iou 0
            plen[s] = pmax[s] - pmin[s];               // == ref's (amax - amin)
        }
        for (int g = 0; g < G_; ++g) {
            float2 gt = smem.tp.gtl[g];
            float glen = gt.y - gt.x;
            u64 m0[4], m1[4];
            #pragma unroll
            for (int s = 0; s < 4; ++s) {
                float inter = fmaxf(fminf(pmax[s], gt.y) - fmaxf(pmin[s], gt.x), 0.0f);
                float uni = plen[s] + glen - inter;    // f32, same op order as ref
                double di = (double)inter;             // exact
                double du = (double)uni;               // exact; uni > 0 always
                m0[s] = __ballot(di > M0_ * du);       // == fl(inter/uni) > 0.5f
                m1[s] = __ballot(di > M1_ * du);       // == fl(inter/uni) > 0.75f
            }
            if (lane == 0) {
                #pragma unroll
                for (int s = 0; s < 4; ++s) {
                    smem.tp.cand[0][g][s * 16 + wv] = m0[s];
                    smem.tp.cand[1][g][s * 16 + wv] = m1[s];
                }
            }
        }
        __syncthreads();   // cand complete + hist complete

        // write per-batch histogram row
        #pragma unroll
        for (int k = 0; k < NBKT / 1024; ++k) {
            int bin = k * 1024 + tid;
            pbh[(size_t)b * NBKT + bin] = (unsigned short)smem.tp.hls[bin];
        }

        // Phase B: wave 0 -> thr 0.5, wave 1 -> thr 0.75. Greedy ballot+ffs.
        if (wv < 2) {
            const int thr_i = wv;
            u64 used = 0ull;                 // proposals [lane*64, lane*64+64)
            for (int g = 0; g < G_; ++g) {
                u64 c = smem.tp.cand[thr_i][g][lane] & ~used;
                u64 ball = __ballot(c != 0ull);
                if (ball) {
                    int fl = __ffsll(ball) - 1;
                    if (lane == fl) used |= (c & (0ull - c));
                }
            }
            int cpop = __popcll(used);
            if (cpop) {
                int j = atomicAdd(&smem.tp.lcnt[thr_i], cpop);
                u64 u = used;
                while (u) {
                    int bit = __ffsll(u) - 1;
                    u &= u - 1;
                    tpIdx[thr_i * NL_ + b * G_ + j++] = b * N_ + lane * 64 + bit;
                }
            }
        }
        __syncthreads();
        if (tid < 2) cnt[tid * B_ + b] = smem.tp.lcnt[tid];
    }
    grid.sync();

    // ====== Phase 1: s1 — 8 bins/block, 4 column-scans in parallel ========
    {
        unsigned* sc = smem.s1.sc[tid >> 8];   // column 0..3, [256]
        const int bb = tid & 255;
        #pragma unroll
        for (int r2 = 0; r2 < 2; ++r2) {
            const int bin = b * 8 + r2 * 4 + (tid >> 8);
            unsigned v = pbh[(size_t)bb * NBKT + bin];
            sc[bb] = v;
            __syncthreads();
            for (int off = 1; off < 256; off <<= 1) {   // inclusive H-S
                unsigned add = (bb >= off) ? sc[bb - off] : 0u;
                __syncthreads();
                sc[bb] += add;
                __syncthreads();
            }
            pbh[(size_t)bb * NBKT + bin] = (unsigned short)(sc[bb] - v); // excl
            if (bb == 255) total[bin] = sc[255];
            __syncthreads();
        }
    }
    grid.sync();

    // ====== Phase 2: scatter (+ per-block s2: scan of 2048 totals) ========
    {
        unsigned* part = smem.sc.lofs;          // reuse [0..1023] as scan temp
        uint2 v2 = ((const uint2*)total)[tid];
        unsigned s = v2.x + v2.y;
        part[tid] = s;
        __syncthreads();
        for (int off = 1; off < 1024; off <<= 1) {   // inclusive H-S
            unsigned add = (tid >= off) ? part[tid - off] : 0u;
            __syncthreads();
            part[tid] += add;
            __syncthreads();
        }
        unsigned base = (tid == 0) ? 0u : part[tid - 1];
        __syncthreads();                        // part reads done
        smem.sc.baseB[2 * tid]     = base;           // bin starts (s2 result)
        smem.sc.baseB[2 * tid + 1] = base + v2.x;
        __syncthreads();
        #pragma unroll
        for (int k = 0; k < 2; ++k) {
            int bin = k * 1024 + tid;
            unsigned bs = smem.sc.baseB[bin];
            if (b == 0) binStartG[bin] = bs;    // publish for rank phase
            smem.sc.baseB[bin] = bs + pbh[(size_t)b * NBKT + bin];
            smem.sc.lofs[bin] = 0u;
        }
        __syncthreads();
        const float* cb = conf + (size_t)b * N_;
        #pragma unroll
        for (int s4 = 0; s4 < 4; ++s4) {
            int n = s4 * 1024 + tid;
            if (n < N_) {
                float c = cb[n];
                unsigned bin = bucket_of(c);
                unsigned lo = atomicAdd(&smem.sc.lofs[bin], 1u);   // LDS atomic
                unsigned idx = (unsigned)(b * N_ + n);
                sKey[smem.sc.baseB[bin] + lo] =
                    ((u64)__float_as_uint(c) << 32) | (u64)(0xFFFFFFFFu - idx);
            }
        }
    }
    grid.sync();

    // ====== Phase 3: rank — wave per TP slot, 6-7 slots per wave ==========
    {
        for (int w = (b << 4) | wv; w < 2 * NL_; w += B_ * 16) {
            const int thr_i = w / NL_;
            const int t = w - thr_i * NL_;
            const int batch = t / G_;
            const int j = t - batch * G_;
            if (j < cnt[thr_i * B_ + batch]) {
                int e = tpIdx[thr_i * NL_ + t];
                float c = conf[e];
                u64 keyE = ((u64)__float_as_uint(c) << 32) |
                           (u64)(0xFFFFFFFFu - (unsigned)e);
                unsigned bin = bucket_of(c);
                unsigned lo = binStartG[bin], n = total[bin];
                int r = M_ - (int)lo - (int)n;   // strictly-better buckets
                for (unsigned base2 = 0; base2 < n; base2 += 64) {
                    unsigned k = base2 + lane;
                    bool pred = (k < n) && (sKey[lo + k] > keyE);
                    r += (int)__popcll(__ballot(pred));
                }
                if (lane == 0) tpRank[thr_i * NL_ + t] = r;
            } else {
                if (lane == 0) tpRank[thr_i * NL_ + t] = M_ + t;   // sentinel
            }
        }
    }
    grid.sync();

    // ====== Phase 4: sortap — blocks 0,1 (one per threshold) ==============
    if (b < 2) {
        const int C = 13;   // 1024*13 = 13312 >= NL_
        const int thr_i = b;

        smem.ap.u2.hist[tid] = 0u; smem.ap.u2.hist[tid + 1024] = 0u;
        __syncthreads();

        // load ranks (coalesced), histogram by rank>>9
        int r[C]; unsigned beta[C];
        #pragma unroll
        for (int k = 0; k < C; ++k) {
            int i = tid + k * 1024;
            if (i < NL_) {
                int rr = tpRank[thr_i * NL_ + i];
                r[k] = rr;
                unsigned bb = ((unsigned)rr) >> 9;
                beta[k] = bb > (NBKT - 1) ? (NBKT - 1) : bb;
                atomicAdd(&smem.ap.u2.hist[beta[k]], 1u);
            } else { r[k] = 0; beta[k] = 0xFFFFFFFFu; }
        }
        __syncthreads();

        // exclusive scan of hist (2048 bins, 2 per thread)
        unsigned h0 = smem.ap.u2.hist[2 * tid], h1 = smem.ap.u2.hist[2 * tid + 1];
        smem.ap.u1.part[tid] = h0 + h1;
        __syncthreads();
        for (int off = 1; off < 1024; off <<= 1) {
            unsigned add = (tid >= off) ? smem.ap.u1.part[tid - off] : 0u;
            __syncthreads();
            smem.ap.u1.part[tid] += add;
            __syncthreads();
        }
        unsigned base = (tid == 0) ? 0u : smem.ap.u1.part[tid - 1];
        __syncthreads();
        smem.ap.u2.hist[2 * tid] = base;        // exclusive bucket starts
        smem.ap.u2.hist[2 * tid + 1] = base + h0;
        __syncthreads();

        // arrival scatter: hist becomes cursor -> ends
        #pragma unroll
        for (int k = 0; k < C; ++k)
            if (beta[k] != 0xFFFFFFFFu) {
                unsigned slot = atomicAdd(&smem.ap.u2.hist[beta[k]], 1u);
                smem.ap.sr[slot] = r[k];
            }
        __syncthreads();
        // hist[b] == end(b); start(b) == (b ? hist[b-1] : 0)

        // exact position = start + #{smaller in bucket}; ranks distinct
        int p[C];
        #pragma unroll
        for (int k = 0; k < C; ++k) {
            if (beta[k] != 0xFFFFFFFFu) {
                unsigned st = (beta[k] == 0u) ? 0u : smem.ap.u2.hist[beta[k] - 1];
                unsigned en = smem.ap.u2.hist[beta[k]];
                int c = 0;
                for (unsigned j = st; j < en; ++j) c += (smem.ap.sr[j] < r[k]);
                p[k] = (int)st + c;
            } else p[k] = -1;
        }
        __syncthreads();
        #pragma unroll
        for (int k = 0; k < C; ++k)             // bijection: every slot written
            if (p[k] >= 0) smem.ap.sr[p[k]] = r[k];
        __syncthreads();

        // ---- AP phase: identical math to R14's ap_kernel ----
        float pr[C]; int rk[C];
        #pragma unroll
        for (int k = 0; k < C; ++k) {
            int i = tid * C + k;
            rk[k] = (i < NL_) ? smem.ap.sr[i] : 0x7FFFFFFF;
            pr[k] = (rk[k] < M_) ? (float)(i + 1) / (float)(rk[k] + 1) : -1.0f;
        }
        float suf[C];
        float run = -1.0f;
        #pragma unroll
        for (int k = C - 1; k >= 0; --k) { run = fmaxf(run, pr[k]); suf[k] = run; }

        smem.ap.u1.cmax[tid] = run;
        __syncthreads();
        for (int off = 1; off < 1024; off <<= 1) {   // inclusive suffix-max
            float v = smem.ap.u1.cmax[tid];
            float o = (tid + off < 1024) ? smem.ap.u1.cmax[tid + off] : -1.0f;
            __syncthreads();
            smem.ap.u1.cmax[tid] = fmaxf(v, o);
            __syncthreads();
        }
        float follow = (tid + 1 < 1024) ? smem.ap.u1.cmax[tid + 1] : -1.0f;

        double acc = 0.0;
        #pragma unroll
        for (int k = 0; k < C; ++k) {
            int i = tid * C + k;
            if (rk[k] >= 1 && rk[k] < M_) {   // global rank 0 excluded by ref
                float smax = fmaxf(suf[k], follow);
                float rhi = (float)(i + 1) / 12800.0f;
                float rlo = (float)i / 12800.0f;
                acc += (double)((rhi - rlo) * smax);
            }
        }
        __syncthreads();
        smem.ap.u2.red[tid] = acc;
        __syncthreads();
        for (int off = 512; off >= 1; off >>= 1) {
            if (tid < off) smem.ap.u2.red[tid] += smem.ap.u2.red[tid + off];
            __syncthreads();
        }
        if (tid == 0) out[thr_i] = (float)smem.ap.u2.red[0];
    }
}

extern "C" void kernel_launch(void* const* d_in, const int* in_sizes, int n_in,
                              void* d_out, int out_size, void* d_ws, size_t ws_size,
                              hipStream_t stream) {
    const float* scores = (const float*)d_in[0];   // [B,N]
    const float* seg    = (const float*)d_in[1];   // [B,N,2]
    const float* gts    = (const float*)d_in[2];   // [B,G,2]
    float* out = (float*)d_out;

    char* p = (char*)d_ws;
    int*            cnt        = (int*)p;             p += 4096;                  // 2KB used
    int*            tpIdx      = (int*)p;             p += 2 * NL_ * 4;           // 100 KB
    int*            tpRank     = (int*)p;             p += 2 * NL_ * 4;           // 100 KB
    unsigned*       total      = (unsigned*)p;        p += NBKT * 4;              // 8 KB
    unsigned*       binStart   = (unsigned*)p;        p += NBKT * 4;              // 8 KB
    unsigned short* pbh        = (unsigned short*)p;  p += (size_t)B_ * NBKT * 2; // 1 MB
    u64*            sKey       = (u64*)p;             p += (size_t)M_ * 8;        // 8 MB
    (void)ws_size; (void)in_sizes; (void)n_in; (void)out_size;

    void* args[] = { (void*)&seg, (void*)&gts, (void*)&scores,
                     (void*)&tpIdx, (void*)&cnt, (void*)&pbh,
                     (void*)&total, (void*)&binStart, (void*)&sKey,
                     (void*)&tpRank, (void*)&out };
    hipLaunchCooperativeKernel(mega_kernel, dim3(B_), dim3(1024),
                               args, 0, stream);
}

// Round 3
// 168.111 us; speedup vs baseline: 1.8337x; 1.8337x over previous
//
#include <hip/hip_runtime.h>

// AP (average precision @ IoU 0.5/0.75) for B=256, N=4000, G=50.
// Strategy: greedy TP matching -> <=50 TPs per (batch,thr); exact stable
// descending-sort ranks of TPs via 2048-bucket counting sort of the 1.024M
// confidences; AP from TP ranks only.
//
// R1: pos 390us latency loop -> LDS. R2-R4: tp stuck ~145us on 1M global
//     hist atomics -> zero-global-atomic design. R5 crash (LDS>64KB).
// R6: 423us. R7: rank one-wave-per-slot; 260. R8: pos1/pos2 split; 204.
// R9: g-outer neutral. R10: bit-exact divide elimination; 191.
// R11: s1/pos2/u64-key bundle neutral; 192.
// R12/R13: cand->global eviction REGRESSED (222us): at grid==CU-count,
//     LDS < 64KB is FREE; eviction added 12.8MB of 8B stores.
// R14: NBKT 1024->2048; 187. R15: pos1+ap -> LDS counting-sort sortap
//     (ranks are DISTINCT ints); 169.8.
// R16: coop-kernel full fusion REGRESSED (308; mega=242us @ 11% VALUBusy):
//     grid.sync spin + rank phase lost its 32-wave/CU latency hiding.
//     LESSONS: (a) dur_us includes the harness ~45us 256MB ws-poison fill;
//     (b) boundaries are only ~3-5us; (c) phase parallelism shape >> launch
//     overhead. Total VALU work is only ~26us, HBM ~80MB -> pipeline is
//     latency/stall dominated, not work dominated.
// R17: revert to R15 structure. Fix s1's column-strided reads (256 lines
//     per block, 2B used per 64B line = 33.5MB traffic for a 1MB array):
//     tile s1 as 64 blocks x 32 bins, line-aligned [256][32] u16 tile,
//     exactly 1MB fetched. Fold s2 into scatter (redundant per-block scan,
//     code path proven absmax-0 inside R16's mega). 6 -> 5 dispatches.

#define B_ 256
#define N_ 4000
#define G_ 50
#define M_ (B_ * N_)        // 1,024,000 proposals total
#define NL_ (B_ * G_)       // 12,800 labels total (= n_labels)
#define NBKT 2048

// exact decision thresholds: thr + 2^-25
#define M0_ 0x1.000001p-1   // 0.5  + 2^-25
#define M1_ 0x1.800001p-1   // 0.75 + 2^-25

typedef unsigned long long u64;

__device__ __forceinline__ unsigned bucket_of(float c) {
    unsigned b = (unsigned)(c * 2048.0f);
    return b > (NBKT - 1) ? (NBKT - 1) : b;
}

// ---- Phase 1: IoU cand masks + greedy (both thr) + LDS histogram. ---------
// One 1024-thread block per batch; grid==256 -> 1 block/CU, LDS is free.
__global__ __launch_bounds__(1024) void tp_kernel(
    const float* __restrict__ seg,    // [B,N,2]
    const float* __restrict__ gts,    // [B,G,2]
    const float* __restrict__ conf,   // [B,N]
    int* __restrict__ tpIdx,          // [2][NL_], slots [b*50, b*50+cnt)
    int* __restrict__ cnt,            // [2][B_]
    unsigned short* __restrict__ pbh) // [B_][NBKT] per-batch histogram
{
    const int tid  = threadIdx.x;
    const int lane = tid & 63;
    const int wv   = tid >> 6;            // wave id 0..15
    const int b    = blockIdx.x;

    __shared__ float2 gtl[G_];            // 400 B
    __shared__ u64 cand[2][G_][64];       // 51.2 KiB
    __shared__ unsigned hls[NBKT];        // 8 KiB
    __shared__ int lcnt[2];               // total 59.8 KiB < 64 KiB

    #pragma unroll
    for (int k = 0; k < NBKT / 1024; ++k) hls[k * 1024 + tid] = 0u;
    if (tid < G_) gtl[tid] = ((const float2*)gts)[b * G_ + tid];
    if (tid < 2) lcnt[tid] = 0;
    __syncthreads();

    // LDS-private histogram of this batch's 4000 scores
    const float* cb = conf + (size_t)b * N_;
    #pragma unroll
    for (int s = 0; s < 4; ++s) {
        int n = s * 1024 + tid;
        if (n < N_) atomicAdd(&hls[bucket_of(cb[n])], 1u);
    }

    // Phase A (g outer, slots inner): props in registers, gt read once per g.
    const float2* sb = (const float2*)(seg + (size_t)b * (N_ * 2));
    float pmin[4], pmax[4], plen[4];
    #pragma unroll
    for (int s = 0; s < 4; ++s) {
        int n = s * 1024 + tid;
        if (n < N_) { float2 v = sb[n]; pmin[s] = v.x; pmax[s] = v.y; }
        else { pmin[s] = 1e9f; pmax[s] = 1e9f; }   // sentinel -> iou 0
        plen[s] = pmax[s] - pmin[s];               // == ref's (amax - amin)
    }
    for (int g = 0; g < G_; ++g) {
        float2 gt = gtl[g];                        // one LDS broadcast per g
        float glen = gt.y - gt.x;
        u64 m0[4], m1[4];
        #pragma unroll
        for (int s = 0; s < 4; ++s) {
            float inter = fmaxf(fminf(pmax[s], gt.y) - fmaxf(pmin[s], gt.x), 0.0f);
            float uni = plen[s] + glen - inter;    // f32, same op order as ref
            double di = (double)inter;             // exact
            double du = (double)uni;               // exact; uni > 0 always
            m0[s] = __ballot(di > M0_ * du);       // == fl(inter/uni) > 0.5f
            m1[s] = __ballot(di > M1_ * du);       // == fl(inter/uni) > 0.75f
        }
        if (lane == 0) {                           // one branch, 8 LDS stores
            #pragma unroll
            for (int s = 0; s < 4; ++s) {
                cand[0][g][s * 16 + wv] = m0[s];
                cand[1][g][s * 16 + wv] = m1[s];
            }
        }
    }
    __syncthreads();   // cand complete + hist complete

    // write per-batch histogram row (u16; per-batch bin count <= 4000)
    #pragma unroll
    for (int k = 0; k < NBKT / 1024; ++k) {
        int bin = k * 1024 + tid;
        pbh[(size_t)b * NBKT + bin] = (unsigned short)hls[bin];
    }

    // Phase B: wave 0 -> thr 0.5, wave 1 -> thr 0.75. Greedy via ballot+ffs.
    if (wv < 2) {
        const int thr_i = wv;
        u64 used = 0ull;                     // proposals [lane*64, lane*64+64)
        for (int g = 0; g < G_; ++g) {
            u64 c = cand[thr_i][g][lane] & ~used;
            u64 ball = __ballot(c != 0ull);
            if (ball) {
                int fl = __ffsll(ball) - 1;  // lowest lane = lowest proposal range
                if (lane == fl) used |= (c & (0ull - c));   // lowest set bit
            }
        }
        int cpop = __popcll(used);
        if (cpop) {
            int j = atomicAdd(&lcnt[thr_i], cpop);   // LDS atomic, block-local
            u64 u = used;
            while (u) {
                int bit = __ffsll(u) - 1;
                u &= u - 1;
                tpIdx[thr_i * NL_ + b * G_ + j++] = b * N_ + lane * 64 + bit;
            }
        }
    }
    __syncthreads();
    if (tid < 2) cnt[tid * B_ + b] = lcnt[tid];
}

// ---- S1: tiled column scan. 64 blocks x 32 bins; tile [256 batches][32] --
// Row t of the tile = 64B line-aligned slice of pbh row t -> every fetched
// line is 100% used; total fetch = exactly the 1MB pbh (was 33.5MB strided).
__global__ __launch_bounds__(256) void s1_kernel(
    unsigned short* __restrict__ pbh,        // [B_][NBKT] -> becomes prefix
    unsigned* __restrict__ total)            // [NBKT]
{
    __shared__ unsigned short tile[256][32]; // 16 KiB
    const int j = blockIdx.x;                // bins [j*32, j*32+32)
    const int t = threadIdx.x;               // batch row
    uint4* dst = (uint4*)&tile[t][0];
    const uint4* src = (const uint4*)(pbh + (size_t)t * NBKT + j * 32);
    #pragma unroll
    for (int k = 0; k < 4; ++k) dst[k] = src[k];      // 64 B, one line
    __syncthreads();
    if (t < 32) {                            // serial exclusive scan per column
        unsigned run = 0;
        for (int b = 0; b < 256; ++b) {      // 2-way LDS bank alias: free
            unsigned v = tile[b][t];
            tile[b][t] = (unsigned short)run;
            run += v;
        }
        total[j * 32 + t] = run;
    }
    __syncthreads();
    uint4* back = (uint4*)(pbh + (size_t)t * NBKT + j * 32);
    #pragma unroll
    for (int k = 0; k < 4; ++k) back[k] = dst[k];     // coalesced write-back
}

// ---- Scatter (+ fused s2: per-block redundant scan of 2048 totals) -------
// key = bits(conf)<<32 | ~idx : u64 ordering == (conf desc, idx asc) exactly.
__global__ __launch_bounds__(1024) void scatter_kernel(
    const float* __restrict__ conf,
    const unsigned short* __restrict__ pbh,  // now the exclusive prefix
    const unsigned* __restrict__ total,
    unsigned* __restrict__ binStartG,        // published by block 0 for rank
    u64* __restrict__ sKey)
{
    __shared__ unsigned baseB[NBKT];   // 8 KiB
    __shared__ unsigned lofs[NBKT];    // 8 KiB
    const int tid = threadIdx.x;
    const int b = blockIdx.x;

    // s2 inlined: inclusive H-S scan of the 2048 bin totals (2 per thread)
    unsigned* part = lofs;                  // reuse as scan temp
    uint2 v2 = ((const uint2*)total)[tid];
    unsigned s = v2.x + v2.y;
    part[tid] = s;
    __syncthreads();
    for (int off = 1; off < 1024; off <<= 1) {
        unsigned add = (tid >= off) ? part[tid - off] : 0u;
        __syncthreads();
        part[tid] += add;
        __syncthreads();
    }
    unsigned base = (tid == 0) ? 0u : part[tid - 1];
    __syncthreads();                        // all part reads done
    baseB[2 * tid]     = base;              // exclusive bin starts (s2 result)
    baseB[2 * tid + 1] = base + v2.x;
    __syncthreads();
    #pragma unroll
    for (int k = 0; k < 2; ++k) {
        int bin = k * 1024 + tid;
        unsigned bs = baseB[bin];
        if (b == 0) binStartG[bin] = bs;    // publish for rank_kernel
        baseB[bin] = bs + pbh[(size_t)b * NBKT + bin];
        lofs[bin] = 0u;
    }
    __syncthreads();

    const float* cb = conf + (size_t)b * N_;
    #pragma unroll
    for (int s4 = 0; s4 < 4; ++s4) {
        int n = s4 * 1024 + tid;
        if (n < N_) {
            float c = cb[n];
            unsigned bin = bucket_of(c);
            unsigned lo = atomicAdd(&lofs[bin], 1u);   // LDS atomic
            unsigned idx = (unsigned)(b * N_ + n);
            sKey[baseB[bin] + lo] = ((u64)__float_as_uint(c) << 32) | (u64)(0xFFFFFFFFu - idx);
        }
    }
}

// ---- Rank: one WAVE per TP slot; lanes stride the ~500-elem bucket --------
__global__ __launch_bounds__(256) void rank_kernel(
    const float* __restrict__ conf,
    const int* __restrict__ tpIdx,
    const int* __restrict__ cnt,
    const unsigned* __restrict__ total,
    const unsigned* __restrict__ binStart,
    const u64* __restrict__ sKey,
    int* __restrict__ tpRank)
{
    const int lane = threadIdx.x & 63;
    const int w = (blockIdx.x << 2) | (threadIdx.x >> 6);   // global wave id
    if (w >= 2 * NL_) return;
    const int thr_i = w / NL_;
    const int t = w - thr_i * NL_;
    const int batch = t / G_;
    const int j = t - batch * G_;

    if (j < cnt[thr_i * B_ + batch]) {
        int e = tpIdx[thr_i * NL_ + t];
        float c = conf[e];
        u64 keyE = ((u64)__float_as_uint(c) << 32) | (u64)(0xFFFFFFFFu - (unsigned)e);
        unsigned bin = bucket_of(c);
        unsigned lo = binStart[bin], n = total[bin];
        int r = M_ - (int)lo - (int)n;   // strictly-better buckets
        for (unsigned base = 0; base < n; base += 64) {
            unsigned k = base + lane;
            bool pred = (k < n) && (sKey[lo + k] > keyE);
            r += (int)__popcll(__ballot(pred));   // wave-uniform partial sum
        }
        if (lane == 0) tpRank[thr_i * NL_ + t] = r;
    } else {
        if (lane == 0) tpRank[thr_i * NL_ + t] = M_ + t;   // distinct sentinel
    }
}

// ---- SortAP: counting sort of the 12800 DISTINCT TP ranks in LDS, then AP.
// One block per threshold. Buckets rank>>9: valid ranks -> beta <= 1999;
// sentinels M_+t -> beta in [2000, 2025]; all < 2048, sort after valids.
__global__ __launch_bounds__(1024) void sortap_kernel(
    const int* __restrict__ tpRank,
    float* __restrict__ out)
{
    const int C = 13;   // 1024*13 = 13312 >= NL_
    union U1 { unsigned part[1024]; float cmax[1024]; };   // 4 KiB
    union U2 { unsigned hist[NBKT]; double red[1024]; };   // 8 KiB
    __shared__ int sr[NL_];            // 51.2 KiB: member list -> sorted ranks
    __shared__ U1 u1;
    __shared__ U2 u2;                  // total 63.4 KiB < 64 KiB
    const int thr_i = blockIdx.x;
    const int t = threadIdx.x;

    u2.hist[t] = 0u; u2.hist[t + 1024] = 0u;
    __syncthreads();

    // load ranks (coalesced), histogram by rank>>9
    int r[C]; unsigned beta[C];
    #pragma unroll
    for (int k = 0; k < C; ++k) {
        int i = t + k * 1024;
        if (i < NL_) {
            int rr = tpRank[thr_i * NL_ + i];
            r[k] = rr;
            unsigned bb = ((unsigned)rr) >> 9;
            beta[k] = bb > (NBKT - 1) ? (NBKT - 1) : bb;
            atomicAdd(&u2.hist[beta[k]], 1u);
        } else { r[k] = 0; beta[k] = 0xFFFFFFFFu; }
    }
    __syncthreads();

    // exclusive scan of hist (2048 bins, 2 per thread; s2-style)
    unsigned h0 = u2.hist[2 * t], h1 = u2.hist[2 * t + 1];
    u1.part[t] = h0 + h1;
    __syncthreads();
    for (int off = 1; off < 1024; off <<= 1) {
        unsigned add = (t >= off) ? u1.part[t - off] : 0u;
        __syncthreads();
        u1.part[t] += add;
        __syncthreads();
    }
    unsigned base = (t == 0) ? 0u : u1.part[t - 1];
    __syncthreads();                       // all part reads done
    u2.hist[2 * t] = base;                 // hist := exclusive bucket starts
    u2.hist[2 * t + 1] = base + h0;
    __syncthreads();

    // arrival scatter: hist becomes per-bucket cursor -> ends
    #pragma unroll
    for (int k = 0; k < C; ++k)
        if (beta[k] != 0xFFFFFFFFu) {
            unsigned slot = atomicAdd(&u2.hist[beta[k]], 1u);
            sr[slot] = r[k];
        }
    __syncthreads();
    // now hist[b] == end(b); start(b) == (b ? hist[b-1] : 0)

    // exact position = start + #{smaller in bucket}; ranks are distinct
    int p[C];
    #pragma unroll
    for (int k = 0; k < C; ++k) {
        if (beta[k] != 0xFFFFFFFFu) {
            unsigned st = (beta[k] == 0u) ? 0u : u2.hist[beta[k] - 1];
            unsigned en = u2.hist[beta[k]];
            int c = 0;
            for (unsigned j = st; j < en; ++j) c += (sr[j] < r[k]);
            p[k] = (int)st + c;
        } else p[k] = -1;
    }
    __syncthreads();                       // member reads done
    #pragma unroll
    for (int k = 0; k < C; ++k)            // bijection: every slot written
        if (p[k] >= 0) sr[p[k]] = r[k];
    __syncthreads();

    // ---- AP phase: identical math to R14's ap_kernel ----
    float pr[C]; int rk[C];
    #pragma unroll
    for (int k = 0; k < C; ++k) {
        int i = t * C + k;
        rk[k] = (i < NL_) ? sr[i] : 0x7FFFFFFF;
        pr[k] = (rk[k] < M_) ? (float)(i + 1) / (float)(rk[k] + 1) : -1.0f;
    }
    float suf[C];
    float run = -1.0f;
    #pragma unroll
    for (int k = C - 1; k >= 0; --k) { run = fmaxf(run, pr[k]); suf[k] = run; }

    u1.cmax[t] = run;
    __syncthreads();
    for (int off = 1; off < 1024; off <<= 1) {   // inclusive suffix-max scan
        float v = u1.cmax[t];
        float o = (t + off < 1024) ? u1.cmax[t + off] : -1.0f;
        __syncthreads();
        u1.cmax[t] = fmaxf(v, o);
        __syncthreads();
    }
    float follow = (t + 1 < 1024) ? u1.cmax[t + 1] : -1.0f;

    double acc = 0.0;
    #pragma unroll
    for (int k = 0; k < C; ++k) {
        int i = t * C + k;
        if (rk[k] >= 1 && rk[k] < M_) {   // global rank 0 excluded by ref curve
            float smax = fmaxf(suf[k], follow);
            float rhi = (float)(i + 1) / 12800.0f;
            float rlo = (float)i / 12800.0f;
            acc += (double)((rhi - rlo) * smax);
        }
    }
    __syncthreads();                       // hist reads long done; red aliases it
    u2.red[t] = acc;
    __syncthreads();
    for (int off = 512; off >= 1; off >>= 1) {
        if (t < off) u2.red[t] += u2.red[t + off];
        __syncthreads();
    }
    if (t == 0) out[thr_i] = (float)u2.red[0];
}

extern "C" void kernel_launch(void* const* d_in, const int* in_sizes, int n_in,
                              void* d_out, int out_size, void* d_ws, size_t ws_size,
                              hipStream_t stream) {
    const float* scores = (const float*)d_in[0];   // [B,N]
    const float* seg    = (const float*)d_in[1];   // [B,N,2]
    const float* gts    = (const float*)d_in[2];   // [B,G,2]
    float* out = (float*)d_out;

    char* p = (char*)d_ws;
    int*            cnt        = (int*)p;             p += 4096;                  // 2KB used
    int*            tpIdx      = (int*)p;             p += 2 * NL_ * 4;           // 100 KB
    int*            tpRank     = (int*)p;             p += 2 * NL_ * 4;           // 100 KB
    unsigned*       total      = (unsigned*)p;        p += NBKT * 4;              // 8 KB
    unsigned*       binStart   = (unsigned*)p;        p += NBKT * 4;              // 8 KB
    unsigned short* pbh        = (unsigned short*)p;  p += (size_t)B_ * NBKT * 2; // 1 MB
    u64*            sKey       = (u64*)p;             p += (size_t)M_ * 8;        // 8 MB
    (void)ws_size; (void)in_sizes; (void)n_in; (void)out_size;

    // No memset: every workspace word read downstream is written upstream.
    tp_kernel<<<B_, 1024, 0, stream>>>(seg, gts, scores, tpIdx, cnt, pbh);
    s1_kernel<<<64, 256, 0, stream>>>(pbh, total);
    scatter_kernel<<<B_, 1024, 0, stream>>>(scores, pbh, total, binStart, sKey);
    rank_kernel<<<(2 * NL_ + 3) / 4, 256, 0, stream>>>(scores, tpIdx, cnt,
                                                       total, binStart, sKey, tpRank);
    sortap_kernel<<<2, 1024, 0, stream>>>(tpRank, out);
}

// Round 4
// 163.755 us; speedup vs baseline: 1.8825x; 1.0266x over previous
//
#include <hip/hip_runtime.h>

// AP (average precision @ IoU 0.5/0.75) for B=256, N=4000, G=50.
// Strategy: greedy TP matching -> <=50 TPs per (batch,thr); exact stable
// descending-sort ranks of TPs via 4096-bucket counting sort of the 1.024M
// confidences; AP from TP ranks only.
//
// R1: pos 390us latency loop -> LDS. R2-R4: tp stuck ~145us on 1M global
//     hist atomics -> zero-global-atomic design. R5 crash (LDS>64KB).
// R6: 423us. R7: rank one-wave-per-slot; 260. R8: pos1/pos2 split; 204.
// R9: g-outer neutral. R10: bit-exact divide elimination; 191.
// R11: s1/pos2/u64-key bundle neutral; 192.
// R12/R13: cand->global eviction REGRESSED (222us): at grid==CU-count,
//     LDS < 64KB is FREE; eviction added 12.8MB of 8B stores.
// R14: NBKT 1024->2048; 187. R15: pos1+ap -> LDS counting-sort sortap
//     (ranks are DISTINCT ints); 169.8.
// R16: coop-kernel full fusion REGRESSED (308; mega=242us @ 11% VALUBusy):
//     grid.sync spin + rank lost 32-wave/CU latency hiding. LESSONS:
//     (a) dur_us carries ~90-105us fixed harness poison/memset cost;
//     (b) boundaries ~3-5us; (c) total VALU work only ~26us, HBM ~80MB.
// R17: s1 tiled line-aligned + s2 folded into scatter: NEUTRAL (168.1).
//     s1's strided reads were L2/L3-absorbed all along. Small phases are
//     small; remaining targets by model: tp ~14us (f64 predicate chain),
//     rank ~8-10us (bucket scans), scatter ~8-10, sortap ~5.
// R18: (1) exact-f32 IoU predicate: fl32(i/u)>thr <=> i>(thr+2^-25)u
//     <=> Sterbenz-exact f32 tests d>e25 / (d-0.25u)>e25 where d=i-0.5u,
//     e25=2^-25*u. Removes ALL f64 from tp's 200-iter inner loop.
//     (2) NBKT 2048->4096: rank scans halve (500->250/bucket); tp hist
//     stays 8KB LDS via u16-packed pairs; sortap keeps own 2048 radix.

#define B_ 256
#define N_ 4000
#define G_ 50
#define M_ (B_ * N_)        // 1,024,000 proposals total
#define NL_ (B_ * G_)       // 12,800 labels total (= n_labels)
#define NBKT 4096           // score-counting-sort buckets
#define SBKT 2048           // sortap's internal rank-radix buckets

typedef unsigned long long u64;

__device__ __forceinline__ unsigned bucket_of(float c) {
    unsigned b = (unsigned)(c * 4096.0f);
    return b > (NBKT - 1) ? (NBKT - 1) : b;
}

// ---- Phase 1: IoU cand masks + greedy (both thr) + LDS histogram. ---------
// One 1024-thread block per batch; grid==256 -> 1 block/CU, LDS is free.
__global__ __launch_bounds__(1024) void tp_kernel(
    const float* __restrict__ seg,    // [B,N,2]
    const float* __restrict__ gts,    // [B,G,2]
    const float* __restrict__ conf,   // [B,N]
    int* __restrict__ tpIdx,          // [2][NL_], slots [b*50, b*50+cnt)
    int* __restrict__ cnt,            // [2][B_]
    unsigned short* __restrict__ pbh) // [B_][NBKT] per-batch histogram
{
    const int tid  = threadIdx.x;
    const int lane = tid & 63;
    const int wv   = tid >> 6;            // wave id 0..15
    const int b    = blockIdx.x;

    __shared__ float2 gtl[G_];            // 400 B
    __shared__ u64 cand[2][G_][64];       // 51.2 KiB
    __shared__ unsigned hls[NBKT / 2];    // 8 KiB (u16-packed bin pairs)
    __shared__ int lcnt[2];               // total 59.8 KiB < 64 KiB

    #pragma unroll
    for (int k = 0; k < NBKT / 2048; ++k) hls[k * 1024 + tid] = 0u;
    if (tid < G_) gtl[tid] = ((const float2*)gts)[b * G_ + tid];
    if (tid < 2) lcnt[tid] = 0;
    __syncthreads();

    // LDS-private histogram; packed u16 pairs (per-batch bin count <= 4000,
    // so no carry across the 16-bit fields).
    const float* cb = conf + (size_t)b * N_;
    #pragma unroll
    for (int s = 0; s < 4; ++s) {
        int n = s * 1024 + tid;
        if (n < N_) {
            unsigned bin = bucket_of(cb[n]);
            atomicAdd(&hls[bin >> 1], 1u << ((bin & 1) * 16));
        }
    }

    // Phase A (g outer, slots inner): props in registers, gt read once per g.
    const float2* sb = (const float2*)(seg + (size_t)b * (N_ * 2));
    float pmin[4], pmax[4], plen[4];
    #pragma unroll
    for (int s = 0; s < 4; ++s) {
        int n = s * 1024 + tid;
        if (n < N_) { float2 v = sb[n]; pmin[s] = v.x; pmax[s] = v.y; }
        else { pmin[s] = 1e9f; pmax[s] = 1e9f; }   // sentinel -> iou 0
        plen[s] = pmax[s] - pmin[s];               // == ref's (amax - amin)
    }
    for (int g = 0; g < G_; ++g) {
        float2 gt = gtl[g];                        // one LDS broadcast per g
        float glen = gt.y - gt.x;
        u64 m0[4], m1[4];
        #pragma unroll
        for (int s = 0; s < 4; ++s) {
            float inter = fmaxf(fminf(pmax[s], gt.y) - fmaxf(pmin[s], gt.x), 0.0f);
            float uni = plen[s] + glen - inter;    // f32, same op order as ref
            // Exact predicate: fl32(inter/uni) > thr  <=>  inter > (thr+2^-25)*uni.
            // d = inter - 0.5*uni is Sterbenz-exact for inter >= 0.25*uni (covers
            // the decision boundary; robustly negative below). e25 = 2^-25*uni is
            // always exact. (d - 0.25*uni) exact for inter in [0.625u, u].
            float e25 = uni * 0x1p-25f;
            float d   = inter - 0.5f * uni;
            m0[s] = __ballot(d > e25);                   // == fl(i/u) > 0.5f
            m1[s] = __ballot((d - 0.25f * uni) > e25);   // == fl(i/u) > 0.75f
        }
        if (lane == 0) {                           // one branch, 8 LDS stores
            #pragma unroll
            for (int s = 0; s < 4; ++s) {
                cand[0][g][s * 16 + wv] = m0[s];
                cand[1][g][s * 16 + wv] = m1[s];
            }
        }
    }
    __syncthreads();   // cand complete + hist complete

    // write per-batch histogram row: packed u32 layout == u16[bin] layout
    {
        unsigned* prow = (unsigned*)(pbh + (size_t)b * NBKT);
        #pragma unroll
        for (int k = 0; k < NBKT / 2048; ++k)
            prow[k * 1024 + tid] = hls[k * 1024 + tid];
    }

    // Phase B: wave 0 -> thr 0.5, wave 1 -> thr 0.75. Greedy via ballot+ffs.
    if (wv < 2) {
        const int thr_i = wv;
        u64 used = 0ull;                     // proposals [lane*64, lane*64+64)
        for (int g = 0; g < G_; ++g) {
            u64 c = cand[thr_i][g][lane] & ~used;
            u64 ball = __ballot(c != 0ull);
            if (ball) {
                int fl = __ffsll(ball) - 1;  // lowest lane = lowest proposal range
                if (lane == fl) used |= (c & (0ull - c));   // lowest set bit
            }
        }
        int cpop = __popcll(used);
        if (cpop) {
            int j = atomicAdd(&lcnt[thr_i], cpop);   // LDS atomic, block-local
            u64 u = used;
            while (u) {
                int bit = __ffsll(u) - 1;
                u &= u - 1;
                tpIdx[thr_i * NL_ + b * G_ + j++] = b * N_ + lane * 64 + bit;
            }
        }
    }
    __syncthreads();
    if (tid < 2) cnt[tid * B_ + b] = lcnt[tid];
}

// ---- S1: tiled column scan. 128 blocks x 32 bins; tile [256 batches][32] --
__global__ __launch_bounds__(256) void s1_kernel(
    unsigned short* __restrict__ pbh,        // [B_][NBKT] -> becomes prefix
    unsigned* __restrict__ total)            // [NBKT]
{
    __shared__ unsigned short tile[256][32]; // 16 KiB
    const int j = blockIdx.x;                // bins [j*32, j*32+32)
    const int t = threadIdx.x;               // batch row
    uint4* dst = (uint4*)&tile[t][0];
    const uint4* src = (const uint4*)(pbh + (size_t)t * NBKT + j * 32);
    #pragma unroll
    for (int k = 0; k < 4; ++k) dst[k] = src[k];      // 64 B, one line
    __syncthreads();
    if (t < 32) {                            // serial exclusive scan per column
        unsigned run = 0;
        for (int b = 0; b < 256; ++b) {      // 2-way LDS bank alias: free
            unsigned v = tile[b][t];
            tile[b][t] = (unsigned short)run;
            run += v;
        }
        total[j * 32 + t] = run;
    }
    __syncthreads();
    uint4* back = (uint4*)(pbh + (size_t)t * NBKT + j * 32);
    #pragma unroll
    for (int k = 0; k < 4; ++k) back[k] = dst[k];     // coalesced write-back
}

// ---- Scatter (+ fused s2: per-block redundant scan of 4096 totals) -------
// key = bits(conf)<<32 | ~idx : u64 ordering == (conf desc, idx asc) exactly.
__global__ __launch_bounds__(1024) void scatter_kernel(
    const float* __restrict__ conf,
    const unsigned short* __restrict__ pbh,  // now the exclusive prefix
    const unsigned* __restrict__ total,
    unsigned* __restrict__ binStartG,        // published by block 0 for rank
    u64* __restrict__ sKey)
{
    __shared__ unsigned baseB[NBKT];   // 16 KiB
    __shared__ unsigned lofs[NBKT];    // 16 KiB
    const int tid = threadIdx.x;
    const int b = blockIdx.x;

    // s2 inlined: inclusive H-S scan of the 4096 bin totals (4 per thread)
    unsigned* part = lofs;                  // reuse first 1024 as scan temp
    uint4 v4 = ((const uint4*)total)[tid];
    unsigned s = v4.x + v4.y + v4.z + v4.w;
    part[tid] = s;
    __syncthreads();
    for (int off = 1; off < 1024; off <<= 1) {
        unsigned add = (tid >= off) ? part[tid - off] : 0u;
        __syncthreads();
        part[tid] += add;
        __syncthreads();
    }
    unsigned base = (tid == 0) ? 0u : part[tid - 1];
    __syncthreads();                        // all part reads done
    baseB[4 * tid]     = base;              // exclusive bin starts (s2 result)
    baseB[4 * tid + 1] = base + v4.x;
    baseB[4 * tid + 2] = base + v4.x + v4.y;
    baseB[4 * tid + 3] = base + v4.x + v4.y + v4.z;
    __syncthreads();
    #pragma unroll
    for (int k = 0; k < 4; ++k) {
        int bin = k * 1024 + tid;
        unsigned bs = baseB[bin];
        if (b == 0) binStartG[bin] = bs;    // publish for rank_kernel
        baseB[bin] = bs + pbh[(size_t)b * NBKT + bin];
        lofs[bin] = 0u;
    }
    __syncthreads();

    const float* cb = conf + (size_t)b * N_;
    #pragma unroll
    for (int s4 = 0; s4 < 4; ++s4) {
        int n = s4 * 1024 + tid;
        if (n < N_) {
            float c = cb[n];
            unsigned bin = bucket_of(c);
            unsigned lo = atomicAdd(&lofs[bin], 1u);   // LDS atomic
            unsigned idx = (unsigned)(b * N_ + n);
            sKey[baseB[bin] + lo] = ((u64)__float_as_uint(c) << 32) | (u64)(0xFFFFFFFFu - idx);
        }
    }
}

// ---- Rank: one WAVE per TP slot; lanes stride the ~250-elem bucket --------
__global__ __launch_bounds__(256) void rank_kernel(
    const float* __restrict__ conf,
    const int* __restrict__ tpIdx,
    const int* __restrict__ cnt,
    const unsigned* __restrict__ total,
    const unsigned* __restrict__ binStart,
    const u64* __restrict__ sKey,
    int* __restrict__ tpRank)
{
    const int lane = threadIdx.x & 63;
    const int w = (blockIdx.x << 2) | (threadIdx.x >> 6);   // global wave id
    if (w >= 2 * NL_) return;
    const int thr_i = w / NL_;
    const int t = w - thr_i * NL_;
    const int batch = t / G_;
    const int j = t - batch * G_;

    if (j < cnt[thr_i * B_ + batch]) {
        int e = tpIdx[thr_i * NL_ + t];
        float c = conf[e];
        u64 keyE = ((u64)__float_as_uint(c) << 32) | (u64)(0xFFFFFFFFu - (unsigned)e);
        unsigned bin = bucket_of(c);
        unsigned lo = binStart[bin], n = total[bin];
        int r = M_ - (int)lo - (int)n;   // strictly-better buckets
        for (unsigned base = 0; base < n; base += 64) {
            unsigned k = base + lane;
            bool pred = (k < n) && (sKey[lo + k] > keyE);
            r += (int)__popcll(__ballot(pred));   // wave-uniform partial sum
        }
        if (lane == 0) tpRank[thr_i * NL_ + t] = r;
    } else {
        if (lane == 0) tpRank[thr_i * NL_ + t] = M_ + t;   // distinct sentinel
    }
}

// ---- SortAP: counting sort of the 12800 DISTINCT TP ranks in LDS, then AP.
// One block per threshold. Own radix: rank>>9 -> SBKT=2048 buckets; valid
// ranks -> beta <= 1999; sentinels M_+t -> beta in [2000, 2025] < 2048.
__global__ __launch_bounds__(1024) void sortap_kernel(
    const int* __restrict__ tpRank,
    float* __restrict__ out)
{
    const int C = 13;   // 1024*13 = 13312 >= NL_
    union U1 { unsigned part[1024]; float cmax[1024]; };   // 4 KiB
    union U2 { unsigned hist[SBKT]; double red[1024]; };   // 8 KiB
    __shared__ int sr[NL_];            // 51.2 KiB: member list -> sorted ranks
    __shared__ U1 u1;
    __shared__ U2 u2;                  // total 63.4 KiB < 64 KiB
    const int thr_i = blockIdx.x;
    const int t = threadIdx.x;

    u2.hist[t] = 0u; u2.hist[t + 1024] = 0u;
    __syncthreads();

    // load ranks (coalesced), histogram by rank>>9
    int r[C]; unsigned beta[C];
    #pragma unroll
    for (int k = 0; k < C; ++k) {
        int i = t + k * 1024;
        if (i < NL_) {
            int rr = tpRank[thr_i * NL_ + i];
            r[k] = rr;
            unsigned bb = ((unsigned)rr) >> 9;
            beta[k] = bb > (SBKT - 1) ? (SBKT - 1) : bb;
            atomicAdd(&u2.hist[beta[k]], 1u);
        } else { r[k] = 0; beta[k] = 0xFFFFFFFFu; }
    }
    __syncthreads();

    // exclusive scan of hist (2048 bins, 2 per thread)
    unsigned h0 = u2.hist[2 * t], h1 = u2.hist[2 * t + 1];
    u1.part[t] = h0 + h1;
    __syncthreads();
    for (int off = 1; off < 1024; off <<= 1) {
        unsigned add = (t >= off) ? u1.part[t - off] : 0u;
        __syncthreads();
        u1.part[t] += add;
        __syncthreads();
    }
    unsigned base = (t == 0) ? 0u : u1.part[t - 1];
    __syncthreads();                       // all part reads done
    u2.hist[2 * t] = base;                 // hist := exclusive bucket starts
    u2.hist[2 * t + 1] = base + h0;
    __syncthreads();

    // arrival scatter: hist becomes per-bucket cursor -> ends
    #pragma unroll
    for (int k = 0; k < C; ++k)
        if (beta[k] != 0xFFFFFFFFu) {
            unsigned slot = atomicAdd(&u2.hist[beta[k]], 1u);
            sr[slot] = r[k];
        }
    __syncthreads();
    // now hist[b] == end(b); start(b) == (b ? hist[b-1] : 0)

    // exact position = start + #{smaller in bucket}; ranks are distinct
    int p[C];
    #pragma unroll
    for (int k = 0; k < C; ++k) {
        if (beta[k] != 0xFFFFFFFFu) {
            unsigned st = (beta[k] == 0u) ? 0u : u2.hist[beta[k] - 1];
            unsigned en = u2.hist[beta[k]];
            int c = 0;
            for (unsigned j = st; j < en; ++j) c += (sr[j] < r[k]);
            p[k] = (int)st + c;
        } else p[k] = -1;
    }
    __syncthreads();                       // member reads done
    #pragma unroll
    for (int k = 0; k < C; ++k)            // bijection: every slot written
        if (p[k] >= 0) sr[p[k]] = r[k];
    __syncthreads();

    // ---- AP phase: identical math to R14's ap_kernel ----
    float pr[C]; int rk[C];
    #pragma unroll
    for (int k = 0; k < C; ++k) {
        int i = t * C + k;
        rk[k] = (i < NL_) ? sr[i] : 0x7FFFFFFF;
        pr[k] = (rk[k] < M_) ? (float)(i + 1) / (float)(rk[k] + 1) : -1.0f;
    }
    float suf[C];
    float run = -1.0f;
    #pragma unroll
    for (int k = C - 1; k >= 0; --k) { run = fmaxf(run, pr[k]); suf[k] = run; }

    u1.cmax[t] = run;
    __syncthreads();
    for (int off = 1; off < 1024; off <<= 1) {   // inclusive suffix-max scan
        float v = u1.cmax[t];
        float o = (t + off < 1024) ? u1.cmax[t + off] : -1.0f;
        __syncthreads();
        u1.cmax[t] = fmaxf(v, o);
        __syncthreads();
    }
    float follow = (t + 1 < 1024) ? u1.cmax[t + 1] : -1.0f;

    double acc = 0.0;
    #pragma unroll
    for (int k = 0; k < C; ++k) {
        int i = t * C + k;
        if (rk[k] >= 1 && rk[k] < M_) {   // global rank 0 excluded by ref curve
            float smax = fmaxf(suf[k], follow);
            float rhi = (float)(i + 1) / 12800.0f;
            float rlo = (float)i / 12800.0f;
            acc += (double)((rhi - rlo) * smax);
        }
    }
    __syncthreads();                       // hist reads long done; red aliases it
    u2.red[t] = acc;
    __syncthreads();
    for (int off = 512; off >= 1; off >>= 1) {
        if (t < off) u2.red[t] += u2.red[t + off];
        __syncthreads();
    }
    if (t == 0) out[thr_i] = (float)u2.red[0];
}

extern "C" void kernel_launch(void* const* d_in, const int* in_sizes, int n_in,
                              void* d_out, int out_size, void* d_ws, size_t ws_size,
                              hipStream_t stream) {
    const float* scores = (const float*)d_in[0];   // [B,N]
    const float* seg    = (const float*)d_in[1];   // [B,N,2]
    const float* gts    = (const float*)d_in[2];   // [B,G,2]
    float* out = (float*)d_out;

    char* p = (char*)d_ws;
    int*            cnt        = (int*)p;             p += 4096;                  // 2KB used
    int*            tpIdx      = (int*)p;             p += 2 * NL_ * 4;           // 100 KB
    int*            tpRank     = (int*)p;             p += 2 * NL_ * 4;           // 100 KB
    unsigned*       total      = (unsigned*)p;        p += NBKT * 4;              // 16 KB
    unsigned*       binStart   = (unsigned*)p;        p += NBKT * 4;              // 16 KB
    unsigned short* pbh        = (unsigned short*)p;  p += (size_t)B_ * NBKT * 2; // 2 MB
    u64*            sKey       = (u64*)p;             p += (size_t)M_ * 8;        // 8 MB
    (void)ws_size; (void)in_sizes; (void)n_in; (void)out_size;

    // No memset: every workspace word read downstream is written upstream.
    tp_kernel<<<B_, 1024, 0, stream>>>(seg, gts, scores, tpIdx, cnt, pbh);
    s1_kernel<<<NBKT / 32, 256, 0, stream>>>(pbh, total);
    scatter_kernel<<<B_, 1024, 0, stream>>>(scores, pbh, total, binStart, sKey);
    rank_kernel<<<(2 * NL_ + 3) / 4, 256, 0, stream>>>(scores, tpIdx, cnt,
                                                       total, binStart, sKey, tpRank);
    sortap_kernel<<<2, 1024, 0, stream>>>(tpRank, out);
}

// Round 5
// 159.029 us; speedup vs baseline: 1.9384x; 1.0297x over previous
//
#include <hip/hip_runtime.h>

// AP (average precision @ IoU 0.5/0.75) for B=256, N=4000, G=50.
// Strategy: greedy TP matching -> <=50 TPs per (batch,thr); exact stable
// descending-sort ranks of TPs via 4096-bucket counting sort of the 1.024M
// confidences; AP from TP ranks only.
//
// R1: pos 390us latency loop -> LDS. R2-R4: tp stuck ~145us on 1M global
//     hist atomics -> zero-global-atomic design. R5 crash (LDS>64KB).
// R6: 423us. R7: rank one-wave-per-slot; 260. R8: pos1/pos2 split; 204.
// R9: g-outer neutral. R10: bit-exact divide elimination; 191.
// R11: s1/pos2/u64-key bundle neutral; 192.
// R12/R13: cand->global eviction REGRESSED (222us): at grid==CU-count,
//     LDS < 64KB is FREE; eviction added 12.8MB of 8B stores.
// R14: NBKT 1024->2048; 187. R15: pos1+ap -> LDS counting-sort sortap
//     (ranks are DISTINCT ints); 169.8.
// R16: coop-kernel full fusion REGRESSED (308; mega=242us @ 11% VALUBusy):
//     grid.sync spin + rank lost 32-wave/CU latency hiding. LESSONS:
//     (a) dur_us carries ~90-105us fixed harness poison/memset cost;
//     (b) boundaries ~3-5us; (c) total VALU work only ~26us, HBM ~80MB.
// R17: s1 tiled line-aligned + s2 folded into scatter: NEUTRAL (168.1).
// R18: exact-f32 IoU predicate (no f64 in tp) + NBKT 4096: 163.8 (-4.4).
// R19: barrier-cost attack: Hillis-Steele scans (20 syncthreads each) ->
//     wave-shuffle scans (2-3 syncthreads), bit-identical results:
//     scatter's s2-scan, sortap's hist-scan + suffix-max scan; s1's
//     serial 256-scan -> 8x32 segmented scan. Double-sum tree kept
//     verbatim (absmax-0 order preserved).

#define B_ 256
#define N_ 4000
#define G_ 50
#define M_ (B_ * N_)        // 1,024,000 proposals total
#define NL_ (B_ * G_)       // 12,800 labels total (= n_labels)
#define NBKT 4096           // score-counting-sort buckets
#define SBKT 2048           // sortap's internal rank-radix buckets

typedef unsigned long long u64;

__device__ __forceinline__ unsigned bucket_of(float c) {
    unsigned b = (unsigned)(c * 4096.0f);
    return b > (NBKT - 1) ? (NBKT - 1) : b;
}

// ---- Phase 1: IoU cand masks + greedy (both thr) + LDS histogram. ---------
// One 1024-thread block per batch; grid==256 -> 1 block/CU, LDS is free.
__global__ __launch_bounds__(1024) void tp_kernel(
    const float* __restrict__ seg,    // [B,N,2]
    const float* __restrict__ gts,    // [B,G,2]
    const float* __restrict__ conf,   // [B,N]
    int* __restrict__ tpIdx,          // [2][NL_], slots [b*50, b*50+cnt)
    int* __restrict__ cnt,            // [2][B_]
    unsigned short* __restrict__ pbh) // [B_][NBKT] per-batch histogram
{
    const int tid  = threadIdx.x;
    const int lane = tid & 63;
    const int wv   = tid >> 6;            // wave id 0..15
    const int b    = blockIdx.x;

    __shared__ float2 gtl[G_];            // 400 B
    __shared__ u64 cand[2][G_][64];       // 51.2 KiB
    __shared__ unsigned hls[NBKT / 2];    // 8 KiB (u16-packed bin pairs)
    __shared__ int lcnt[2];               // total 59.8 KiB < 64 KiB

    #pragma unroll
    for (int k = 0; k < NBKT / 2048; ++k) hls[k * 1024 + tid] = 0u;
    if (tid < G_) gtl[tid] = ((const float2*)gts)[b * G_ + tid];
    if (tid < 2) lcnt[tid] = 0;
    __syncthreads();

    // LDS-private histogram; packed u16 pairs (per-batch bin count <= 4000,
    // so no carry across the 16-bit fields).
    const float* cb = conf + (size_t)b * N_;
    #pragma unroll
    for (int s = 0; s < 4; ++s) {
        int n = s * 1024 + tid;
        if (n < N_) {
            unsigned bin = bucket_of(cb[n]);
            atomicAdd(&hls[bin >> 1], 1u << ((bin & 1) * 16));
        }
    }

    // Phase A (g outer, slots inner): props in registers, gt read once per g.
    const float2* sb = (const float2*)(seg + (size_t)b * (N_ * 2));
    float pmin[4], pmax[4], plen[4];
    #pragma unroll
    for (int s = 0; s < 4; ++s) {
        int n = s * 1024 + tid;
        if (n < N_) { float2 v = sb[n]; pmin[s] = v.x; pmax[s] = v.y; }
        else { pmin[s] = 1e9f; pmax[s] = 1e9f; }   // sentinel -> iou 0
        plen[s] = pmax[s] - pmin[s];               // == ref's (amax - amin)
    }
    for (int g = 0; g < G_; ++g) {
        float2 gt = gtl[g];                        // one LDS broadcast per g
        float glen = gt.y - gt.x;
        u64 m0[4], m1[4];
        #pragma unroll
        for (int s = 0; s < 4; ++s) {
            float inter = fmaxf(fminf(pmax[s], gt.y) - fmaxf(pmin[s], gt.x), 0.0f);
            float uni = plen[s] + glen - inter;    // f32, same op order as ref
            // Exact predicate: fl32(inter/uni) > thr  <=>  inter > (thr+2^-25)*uni.
            // d = inter - 0.5*uni is Sterbenz-exact for inter >= 0.25*uni (covers
            // the decision boundary; robustly negative below). e25 = 2^-25*uni is
            // always exact. (d - 0.25*uni) exact for inter in [0.625u, u].
            float e25 = uni * 0x1p-25f;
            float d   = inter - 0.5f * uni;
            m0[s] = __ballot(d > e25);                   // == fl(i/u) > 0.5f
            m1[s] = __ballot((d - 0.25f * uni) > e25);   // == fl(i/u) > 0.75f
        }
        if (lane == 0) {                           // one branch, 8 LDS stores
            #pragma unroll
            for (int s = 0; s < 4; ++s) {
                cand[0][g][s * 16 + wv] = m0[s];
                cand[1][g][s * 16 + wv] = m1[s];
            }
        }
    }
    __syncthreads();   // cand complete + hist complete

    // write per-batch histogram row: packed u32 layout == u16[bin] layout
    {
        unsigned* prow = (unsigned*)(pbh + (size_t)b * NBKT);
        #pragma unroll
        for (int k = 0; k < NBKT / 2048; ++k)
            prow[k * 1024 + tid] = hls[k * 1024 + tid];
    }

    // Phase B: wave 0 -> thr 0.5, wave 1 -> thr 0.75. Greedy via ballot+ffs.
    if (wv < 2) {
        const int thr_i = wv;
        u64 used = 0ull;                     // proposals [lane*64, lane*64+64)
        for (int g = 0; g < G_; ++g) {
            u64 c = cand[thr_i][g][lane] & ~used;
            u64 ball = __ballot(c != 0ull);
            if (ball) {
                int fl = __ffsll(ball) - 1;  // lowest lane = lowest proposal range
                if (lane == fl) used |= (c & (0ull - c));   // lowest set bit
            }
        }
        int cpop = __popcll(used);
        if (cpop) {
            int j = atomicAdd(&lcnt[thr_i], cpop);   // LDS atomic, block-local
            u64 u = used;
            while (u) {
                int bit = __ffsll(u) - 1;
                u &= u - 1;
                tpIdx[thr_i * NL_ + b * G_ + j++] = b * N_ + lane * 64 + bit;
            }
        }
    }
    __syncthreads();
    if (tid < 2) cnt[tid * B_ + b] = lcnt[tid];
}

// ---- S1: tiled column scan. 128 blocks x 32 bins; tile [256 batches][32] --
// 8 segs x 32 cols segmented scan (two tile passes) instead of 32-thread
// serial 256-scan.
__global__ __launch_bounds__(256) void s1_kernel(
    unsigned short* __restrict__ pbh,        // [B_][NBKT] -> becomes prefix
    unsigned* __restrict__ total)            // [NBKT]
{
    __shared__ unsigned short tile[256][32]; // 16 KiB
    __shared__ unsigned segsum[8][32];       // 1 KiB
    const int j = blockIdx.x;                // bins [j*32, j*32+32)
    const int t = threadIdx.x;               // batch row (for load/store)
    uint4* dst = (uint4*)&tile[t][0];
    const uint4* src = (const uint4*)(pbh + (size_t)t * NBKT + j * 32);
    #pragma unroll
    for (int k = 0; k < 4; ++k) dst[k] = src[k];      // 64 B, one line
    __syncthreads();

    const int col = t & 31, seg = t >> 5;    // 8 segments of 32 batches
    unsigned run = 0;
    #pragma unroll
    for (int i = 0; i < 32; ++i) run += tile[seg * 32 + i][col];
    segsum[seg][col] = run;
    __syncthreads();
    unsigned off0 = 0;
    #pragma unroll
    for (int s = 0; s < 8; ++s) off0 += (s < seg) ? segsum[s][col] : 0u;
    if (seg == 7) total[j * 32 + col] = off0 + segsum[7][col];
    unsigned run2 = off0;                    // exclusive prefix write-back
    #pragma unroll
    for (int i = 0; i < 32; ++i) {
        unsigned v = tile[seg * 32 + i][col];
        tile[seg * 32 + i][col] = (unsigned short)run2;
        run2 += v;
    }
    __syncthreads();
    uint4* back = (uint4*)(pbh + (size_t)t * NBKT + j * 32);
    #pragma unroll
    for (int k = 0; k < 4; ++k) back[k] = dst[k];     // coalesced write-back
}

// ---- Scatter (+ fused s2: wave-shuffle scan of 4096 totals) --------------
// key = bits(conf)<<32 | ~idx : u64 ordering == (conf desc, idx asc) exactly.
__global__ __launch_bounds__(1024) void scatter_kernel(
    const float* __restrict__ conf,
    const unsigned short* __restrict__ pbh,  // now the exclusive prefix
    const unsigned* __restrict__ total,
    unsigned* __restrict__ binStartG,        // published by block 0 for rank
    u64* __restrict__ sKey)
{
    __shared__ unsigned baseB[NBKT];   // 16 KiB
    __shared__ unsigned lofs[NBKT];    // 16 KiB
    __shared__ unsigned wtot[16];
    const int tid = threadIdx.x;
    const int lane = tid & 63;
    const int wv = tid >> 6;
    const int b = blockIdx.x;

    // s2 inlined: shuffle-based exclusive scan of 4096 totals (4/thread)
    uint4 v4 = ((const uint4*)total)[tid];
    unsigned own = v4.x + v4.y + v4.z + v4.w;
    unsigned inc = own;
    #pragma unroll
    for (int off = 1; off < 64; off <<= 1) {
        unsigned o = __shfl_up(inc, off, 64);
        if (lane >= off) inc += o;
    }
    if (lane == 63) wtot[wv] = inc;
    __syncthreads();
    if (wv == 0) {                          // exclusive scan of 16 wave totals
        unsigned w = (lane < 16) ? wtot[lane] : 0u;
        unsigned wi = w;
        #pragma unroll
        for (int off = 1; off < 16; off <<= 1) {
            unsigned o = __shfl_up(wi, off, 64);
            if (lane >= off) wi += o;
        }
        if (lane < 16) wtot[lane] = wi - w;
    }
    __syncthreads();
    unsigned start = (inc - own) + wtot[wv];     // exclusive global prefix
    baseB[4 * tid]     = start;                  // exclusive bin starts
    baseB[4 * tid + 1] = start + v4.x;
    baseB[4 * tid + 2] = start + v4.x + v4.y;
    baseB[4 * tid + 3] = start + v4.x + v4.y + v4.z;
    __syncthreads();
    #pragma unroll
    for (int k = 0; k < 4; ++k) {
        int bin = k * 1024 + tid;
        unsigned bs = baseB[bin];
        if (b == 0) binStartG[bin] = bs;    // publish for rank_kernel
        baseB[bin] = bs + pbh[(size_t)b * NBKT + bin];
        lofs[bin] = 0u;
    }
    __syncthreads();

    const float* cb = conf + (size_t)b * N_;
    #pragma unroll
    for (int s4 = 0; s4 < 4; ++s4) {
        int n = s4 * 1024 + tid;
        if (n < N_) {
            float c = cb[n];
            unsigned bin = bucket_of(c);
            unsigned lo = atomicAdd(&lofs[bin], 1u);   // LDS atomic
            unsigned idx = (unsigned)(b * N_ + n);
            sKey[baseB[bin] + lo] = ((u64)__float_as_uint(c) << 32) | (u64)(0xFFFFFFFFu - idx);
        }
    }
}

// ---- Rank: one WAVE per TP slot; lanes stride the ~250-elem bucket --------
__global__ __launch_bounds__(256) void rank_kernel(
    const float* __restrict__ conf,
    const int* __restrict__ tpIdx,
    const int* __restrict__ cnt,
    const unsigned* __restrict__ total,
    const unsigned* __restrict__ binStart,
    const u64* __restrict__ sKey,
    int* __restrict__ tpRank)
{
    const int lane = threadIdx.x & 63;
    const int w = (blockIdx.x << 2) | (threadIdx.x >> 6);   // global wave id
    if (w >= 2 * NL_) return;
    const int thr_i = w / NL_;
    const int t = w - thr_i * NL_;
    const int batch = t / G_;
    const int j = t - batch * G_;

    if (j < cnt[thr_i * B_ + batch]) {
        int e = tpIdx[thr_i * NL_ + t];
        float c = conf[e];
        u64 keyE = ((u64)__float_as_uint(c) << 32) | (u64)(0xFFFFFFFFu - (unsigned)e);
        unsigned bin = bucket_of(c);
        unsigned lo = binStart[bin], n = total[bin];
        int r = M_ - (int)lo - (int)n;   // strictly-better buckets
        for (unsigned base = 0; base < n; base += 64) {
            unsigned k = base + lane;
            bool pred = (k < n) && (sKey[lo + k] > keyE);
            r += (int)__popcll(__ballot(pred));   // wave-uniform partial sum
        }
        if (lane == 0) tpRank[thr_i * NL_ + t] = r;
    } else {
        if (lane == 0) tpRank[thr_i * NL_ + t] = M_ + t;   // distinct sentinel
    }
}

// ---- SortAP: counting sort of the 12800 DISTINCT TP ranks in LDS, then AP.
// One block per threshold. Own radix: rank>>9 -> SBKT=2048 buckets; valid
// ranks -> beta <= 1999; sentinels M_+t -> beta in [2000, 2025] < 2048.
__global__ __launch_bounds__(1024) void sortap_kernel(
    const int* __restrict__ tpRank,
    float* __restrict__ out)
{
    const int C = 13;   // 1024*13 = 13312 >= NL_
    union U1 { unsigned wtot[16]; float wmaxs[16]; };
    union U2 { unsigned hist[SBKT]; double red[1024]; };   // 8 KiB
    __shared__ int sr[NL_];            // 51.2 KiB: member list -> sorted ranks
    __shared__ U1 u1;
    __shared__ U2 u2;
    const int thr_i = blockIdx.x;
    const int t = threadIdx.x;
    const int lane = t & 63;
    const int wv = t >> 6;

    u2.hist[t] = 0u; u2.hist[t + 1024] = 0u;
    __syncthreads();

    // load ranks (coalesced), histogram by rank>>9
    int r[C]; unsigned beta[C];
    #pragma unroll
    for (int k = 0; k < C; ++k) {
        int i = t + k * 1024;
        if (i < NL_) {
            int rr = tpRank[thr_i * NL_ + i];
            r[k] = rr;
            unsigned bb = ((unsigned)rr) >> 9;
            beta[k] = bb > (SBKT - 1) ? (SBKT - 1) : bb;
            atomicAdd(&u2.hist[beta[k]], 1u);
        } else { r[k] = 0; beta[k] = 0xFFFFFFFFu; }
    }
    __syncthreads();

    // shuffle-based exclusive scan of hist (2048 bins, 2/thread)
    unsigned h0 = u2.hist[2 * t], h1 = u2.hist[2 * t + 1];
    unsigned own = h0 + h1;
    unsigned inc = own;
    #pragma unroll
    for (int off = 1; off < 64; off <<= 1) {
        unsigned o = __shfl_up(inc, off, 64);
        if (lane >= off) inc += o;
    }
    if (lane == 63) u1.wtot[wv] = inc;
    __syncthreads();
    if (wv == 0) {
        unsigned w = (lane < 16) ? u1.wtot[lane] : 0u;
        unsigned wi = w;
        #pragma unroll
        for (int off = 1; off < 16; off <<= 1) {
            unsigned o = __shfl_up(wi, off, 64);
            if (lane >= off) wi += o;
        }
        if (lane < 16) u1.wtot[lane] = wi - w;
    }
    __syncthreads();
    unsigned base = (inc - own) + u1.wtot[wv];   // exclusive prefix of own
    __syncthreads();                             // all u1 reads done
    u2.hist[2 * t] = base;                 // hist := exclusive bucket starts
    u2.hist[2 * t + 1] = base + h0;
    __syncthreads();

    // arrival scatter: hist becomes per-bucket cursor -> ends
    #pragma unroll
    for (int k = 0; k < C; ++k)
        if (beta[k] != 0xFFFFFFFFu) {
            unsigned slot = atomicAdd(&u2.hist[beta[k]], 1u);
            sr[slot] = r[k];
        }
    __syncthreads();
    // now hist[b] == end(b); start(b) == (b ? hist[b-1] : 0)

    // exact position = start + #{smaller in bucket}; ranks are distinct
    int p[C];
    #pragma unroll
    for (int k = 0; k < C; ++k) {
        if (beta[k] != 0xFFFFFFFFu) {
            unsigned st = (beta[k] == 0u) ? 0u : u2.hist[beta[k] - 1];
            unsigned en = u2.hist[beta[k]];
            int c = 0;
            for (unsigned j = st; j < en; ++j) c += (sr[j] < r[k]);
            p[k] = (int)st + c;
        } else p[k] = -1;
    }
    __syncthreads();                       // member reads done
    #pragma unroll
    for (int k = 0; k < C; ++k)            // bijection: every slot written
        if (p[k] >= 0) sr[p[k]] = r[k];
    __syncthreads();

    // ---- AP phase: identical math to R14's ap_kernel ----
    float pr[C]; int rk[C];
    #pragma unroll
    for (int k = 0; k < C; ++k) {
        int i = t * C + k;
        rk[k] = (i < NL_) ? sr[i] : 0x7FFFFFFF;
        pr[k] = (rk[k] < M_) ? (float)(i + 1) / (float)(rk[k] + 1) : -1.0f;
    }
    float suf[C];
    float run = -1.0f;
    #pragma unroll
    for (int k = C - 1; k >= 0; --k) { run = fmaxf(run, pr[k]); suf[k] = run; }

    // shuffle-based suffix max: follow(t) = max over threads > t of run
    float m = run;
    #pragma unroll
    for (int off = 1; off < 64; off <<= 1) {
        float o = __shfl_down(m, off, 64);
        if (lane + off < 64) m = fmaxf(m, o);
    }
    float f_in = __shfl_down(m, 1, 64);    // suffix from lane+1 in-wave
    if (lane == 63) f_in = -1.0f;
    if (lane == 0) u1.wmaxs[wv] = m;       // wave max
    __syncthreads();
    if (wv == 0) {
        float wm = (lane < 16) ? u1.wmaxs[lane] : -1.0f;
        float mi = wm;
        #pragma unroll
        for (int off = 1; off < 16; off <<= 1) {
            float o = __shfl_down(mi, off, 64);
            if (lane + off < 64) mi = fmaxf(mi, o);
        }
        float fw = __shfl_down(mi, 1, 64); // suffix from wave lane+1
        if (lane >= 15) fw = -1.0f;
        if (lane < 16) u1.wmaxs[lane] = fw;
    }
    __syncthreads();
    float follow = fmaxf(f_in, u1.wmaxs[wv]);

    double acc = 0.0;
    #pragma unroll
    for (int k = 0; k < C; ++k) {
        int i = t * C + k;
        if (rk[k] >= 1 && rk[k] < M_) {   // global rank 0 excluded by ref curve
            float smax = fmaxf(suf[k], follow);
            float rhi = (float)(i + 1) / 12800.0f;
            float rlo = (float)i / 12800.0f;
            acc += (double)((rhi - rlo) * smax);
        }
    }
    __syncthreads();                       // hist reads long done; red aliases it
    u2.red[t] = acc;
    __syncthreads();
    for (int off = 512; off >= 1; off >>= 1) {
        if (t < off) u2.red[t] += u2.red[t + off];
        __syncthreads();
    }
    if (t == 0) out[thr_i] = (float)u2.red[0];
}

extern "C" void kernel_launch(void* const* d_in, const int* in_sizes, int n_in,
                              void* d_out, int out_size, void* d_ws, size_t ws_size,
                              hipStream_t stream) {
    const float* scores = (const float*)d_in[0];   // [B,N]
    const float* seg    = (const float*)d_in[1];   // [B,N,2]
    const float* gts    = (const float*)d_in[2];   // [B,G,2]
    float* out = (float*)d_out;

    char* p = (char*)d_ws;
    int*            cnt        = (int*)p;             p += 4096;                  // 2KB used
    int*            tpIdx      = (int*)p;             p += 2 * NL_ * 4;           // 100 KB
    int*            tpRank     = (int*)p;             p += 2 * NL_ * 4;           // 100 KB
    unsigned*       total      = (unsigned*)p;        p += NBKT * 4;              // 16 KB
    unsigned*       binStart   = (unsigned*)p;        p += NBKT * 4;              // 16 KB
    unsigned short* pbh        = (unsigned short*)p;  p += (size_t)B_ * NBKT * 2; // 2 MB
    u64*            sKey       = (u64*)p;             p += (size_t)M_ * 8;        // 8 MB
    (void)ws_size; (void)in_sizes; (void)n_in; (void)out_size;

    // No memset: every workspace word read downstream is written upstream.
    tp_kernel<<<B_, 1024, 0, stream>>>(seg, gts, scores, tpIdx, cnt, pbh);
    s1_kernel<<<NBKT / 32, 256, 0, stream>>>(pbh, total);
    scatter_kernel<<<B_, 1024, 0, stream>>>(scores, pbh, total, binStart, sKey);
    rank_kernel<<<(2 * NL_ + 3) / 4, 256, 0, stream>>>(scores, tpIdx, cnt,
                                                       total, binStart, sKey, tpRank);
    sortap_kernel<<<2, 1024, 0, stream>>>(tpRank, out);
}